// Round 7
// baseline (269.530 us; speedup 1.0000x reference)
//
#include <hip/hip_runtime.h>
#include <hip/hip_bf16.h>

typedef short short8 __attribute__((ext_vector_type(8)));
typedef float f32x4 __attribute__((ext_vector_type(4)));
typedef float f32x16 __attribute__((ext_vector_type(16)));

#define MFMA16(a, b, c) __builtin_amdgcn_mfma_f32_16x16x32_bf16((a), (b), (c), 0, 0, 0)
#define MFMA32(a, b, c) __builtin_amdgcn_mfma_f32_32x32x16_bf16((a), (b), (c), 0, 0, 0)

// async global->LDS, 16B per lane; LDS dest = wave-uniform base + lane*16
#define GLOAD16(gp, lp)                                                    \
    __builtin_amdgcn_global_load_lds(                                      \
        (const __attribute__((address_space(1))) unsigned int*)(gp),       \
        (__attribute__((address_space(3))) unsigned int*)(lp), 16, 0, 0)

__device__ __forceinline__ unsigned short f2b(float x) {
    unsigned int u = __float_as_uint(x);
    unsigned int r = u + 0x7FFFu + ((u >> 16) & 1u);
    return (unsigned short)(r >> 16);
}

#if __has_builtin(__builtin_amdgcn_cvt_pk_bf16_f32)
__device__ __forceinline__ unsigned pack2(float a, float b) {
    auto v = __builtin_amdgcn_cvt_pk_bf16_f32(a, b);
    unsigned u;
    __builtin_memcpy(&u, &v, 4);
    return u;
}
#else
__device__ __forceinline__ unsigned pack2(float a, float b) {
    return (unsigned)f2b(a) | ((unsigned)f2b(b) << 16);
}
#endif

// ---------------------------------------------------------------- x -> bf16
__global__ __launch_bounds__(256) void cast4_kernel(const float* __restrict__ in,
                                                    unsigned short* __restrict__ out,
                                                    int n4) {
    int i = blockIdx.x * 256 + threadIdx.x;
    if (i < n4) {
        float4 v = ((const float4*)in)[i];
        ushort4 o;
        o.x = f2b(v.x); o.y = f2b(v.y); o.z = f2b(v.z); o.w = f2b(v.w);
        ((ushort4*)out)[i] = o;
    }
}

// ---------------------------------------------------------------- weights: f32 KxN -> bf16 NxK (LDS-tiled)
__global__ __launch_bounds__(256) void transpose_cast_f32(const float* __restrict__ in,
                                                          unsigned short* __restrict__ out,
                                                          int K, int N) {
    __shared__ unsigned short Ls[64 * 66];
    const int k0 = blockIdx.y * 64, n0 = blockIdx.x * 64;
    const int tid = threadIdx.x;
    const int krow = tid >> 4, nc4 = (tid & 15) * 4;
#pragma unroll
    for (int p = 0; p < 4; p++) {
        float4 v = *(const float4*)(in + (size_t)(k0 + krow + p * 16) * N + n0 + nc4);
        unsigned* d32 = (unsigned*)(Ls + (krow + p * 16) * 66 + nc4);
        d32[0] = pack2(v.x, v.y);
        d32[1] = pack2(v.z, v.w);
    }
    __syncthreads();
    const int n = tid >> 3, kc = (tid & 7) * 8;
#pragma unroll
    for (int p = 0; p < 2; p++) {
        int nn = n + p * 32;
        unsigned short w[8];
#pragma unroll
        for (int j = 0; j < 8; j++) w[j] = Ls[(kc + j) * 66 + nn];
        *(short8*)(out + (size_t)(n0 + nn) * K + k0 + kc) = *(short8*)w;
    }
}

// ---------------------------------------------------------------- QKV GEMM (32x32x16, BK=64, fused V transpose)
// A[8192][1024] * wqkvT[3072][1024]^T. Col-blocks route: [0,1024)->Qb (scaled),
// [1024,2048)->Kb, [2048,3072)->Vt[b*16+h][64 d][2048 t] via LDS-bounce transpose.
// BK=64: 16 MFMA32/wave per barrier-pair (was 8) -> half the barrier drains.
// Panels 128x64, rows = full bank wrap -> XOR chunk swizzle (ks*2+hi)^(l32&7).
__global__ __launch_bounds__(256) void gemm_qkv(const unsigned short* __restrict__ A,
                                                const unsigned short* __restrict__ Bt,
                                                unsigned short* __restrict__ Qb,
                                                unsigned short* __restrict__ Kb,
                                                unsigned short* __restrict__ Vt) {
    const int K = 1024, lda = 1024;
    __shared__ unsigned short As[128 * 64]; // 16KB (reused as bounce buffer)
    __shared__ unsigned short Bs[128 * 64]; // 16KB

    const int tid  = threadIdx.x;
    const int wave = tid >> 6;
    const int lane = tid & 63;
    const int l32  = lane & 31;
    const int hi   = lane >> 5;
    const int m0 = blockIdx.y * 128;
    const int n0 = blockIdx.x * 128;
    const int wm = (wave >> 1) * 64;
    const int wn = (wave & 1) * 64;

    // staging: chunk = 8 rows x 64 cols; lane -> row lane>>3, phys 16B-chunk lane&7,
    // source col chunk = (lane&7) ^ (lane>>3)  (inverse of the frag-read swizzle)
    const int rl = lane >> 3;
    const int sc = ((lane & 7) ^ rl) * 8;

    const unsigned short* Ag[4]; unsigned short* Al[4];
    const unsigned short* Bg[4]; unsigned short* Bl[4];
#pragma unroll
    for (int cc = 0; cc < 4; cc++) {
        Ag[cc] = A  + (size_t)(m0 + wave * 32 + cc * 8 + rl) * lda + sc;
        Bg[cc] = Bt + (size_t)(n0 + wave * 32 + cc * 8 + rl) * K + sc;
        Al[cc] = As + (wave * 4 + cc) * 512;
        Bl[cc] = Bs + (wave * 4 + cc) * 512;
    }

    f32x16 acc[2][2] = {};

    for (int k0 = 0; k0 < K; k0 += 64) {
        __syncthreads();
#pragma unroll
        for (int cc = 0; cc < 4; cc++) GLOAD16(Ag[cc] + k0, Al[cc]);
#pragma unroll
        for (int cc = 0; cc < 4; cc++) GLOAD16(Bg[cc] + k0, Bl[cc]);
        __syncthreads();

#pragma unroll
        for (int ks = 0; ks < 4; ks++) {
            const int ch = (((ks * 2 + hi) ^ (l32 & 7))) * 8;
            short8 a0 = *(const short8*)(As + (wm + l32) * 64 + ch);
            short8 a1 = *(const short8*)(As + (wm + 32 + l32) * 64 + ch);
            short8 b0 = *(const short8*)(Bs + (wn + l32) * 64 + ch);
            short8 b1 = *(const short8*)(Bs + (wn + 32 + l32) * 64 + ch);
            acc[0][0] = MFMA32(a0, b0, acc[0][0]);
            acc[0][1] = MFMA32(a0, b1, acc[0][1]);
            acc[1][0] = MFMA32(a1, b0, acc[1][0]);
            acc[1][1] = MFMA32(a1, b1, acc[1][1]);
        }
    }

    if (n0 < 2048) {
        unsigned short* outp = (n0 < 1024) ? Qb : Kb;
        const int cb = (n0 < 1024) ? n0 : n0 - 1024;
        const float QS = (n0 < 1024) ? 0.125f * 1.44269504f : 1.0f;
#pragma unroll
        for (int i = 0; i < 2; i++)
#pragma unroll
            for (int j = 0; j < 2; j++)
#pragma unroll
                for (int r = 0; r < 16; r++) {
                    int row = m0 + wm + i * 32 + (r & 3) + 8 * (r >> 2) + 4 * hi;
                    int col = cb + wn + j * 32 + l32;
                    outp[(size_t)row * 1024 + col] = f2b(acc[i][j][r] * QS);
                }
    } else {
        // V: transpose via LDS bounce. [col][row] layout, word = c*64 + ((row>>1) ^ 4*(c&7)).
        const int b = m0 >> 11;
        const int t0b = m0 & 2047; // within-batch t base
        const int hbase = (n0 - 2048) >> 6;
        unsigned short* smem = As; // 16KB bounce
        __syncthreads(); // all frag reads of last K-step done before smem reuse
#pragma unroll
        for (int p = 0; p < 2; p++) {
            if ((wave & 1) == p) {
#pragma unroll
                for (int i = 0; i < 2; i++)
#pragma unroll
                    for (int j = 0; j < 2; j++) {
                        const int c = j * 32 + l32;
#pragma unroll
                        for (int rg = 0; rg < 4; rg++) {
                            const int rowbase = wm + i * 32 + rg * 8 + 4 * hi;
                            uint2 v;
                            v.x = pack2(acc[i][j][4 * rg + 0], acc[i][j][4 * rg + 1]);
                            v.y = pack2(acc[i][j][4 * rg + 2], acc[i][j][4 * rg + 3]);
                            const int w = c * 64 + ((rowbase >> 1) ^ (4 * (c & 7)));
                            *(uint2*)(smem + 2 * w) = v;
                        }
                    }
            }
            __syncthreads();
#pragma unroll
            for (int it = 0; it < 4; it++) {
                const int id = it * 256 + tid;
                const int c = id >> 4, rg = id & 15;
                const int w = c * 64 + ((rg * 4) ^ (4 * (c & 7)));
                short8 v = *(const short8*)(smem + 2 * w);
                const int h = hbase + p;
                *(short8*)(Vt + ((size_t)((b * 16 + h) * 64 + c)) * 2048 + t0b + rg * 8) = v;
            }
            __syncthreads();
        }
    }
}

// ---------------------------------------------------------------- out-proj GEMM (32x32x16, 64x128 tile, BK=64)
__global__ __launch_bounds__(256) void gemm_out(const unsigned short* __restrict__ A,
                                                const unsigned short* __restrict__ Bt,
                                                float* __restrict__ C) {
    const int K = 1024, lda = 1024;
    __shared__ unsigned short As[64 * 64];   // 8KB
    __shared__ unsigned short Bs[128 * 64];  // 16KB

    const int tid  = threadIdx.x;
    const int wave = tid >> 6;
    const int lane = tid & 63;
    const int l32  = lane & 31;
    const int hi   = lane >> 5;
    const int m0 = blockIdx.y * 64;
    const int n0 = blockIdx.x * 128;
    const int wm = (wave >> 1) * 32;
    const int wn = (wave & 1) * 64;

    const int rl = lane >> 3;
    const int sc = ((lane & 7) ^ rl) * 8;

    const unsigned short* Ag[2]; unsigned short* Al[2];
#pragma unroll
    for (int cc = 0; cc < 2; cc++) {
        Ag[cc] = A + (size_t)(m0 + wave * 16 + cc * 8 + rl) * lda + sc;
        Al[cc] = As + (wave * 2 + cc) * 512;
    }
    const unsigned short* Bg[4]; unsigned short* Bl[4];
#pragma unroll
    for (int cc = 0; cc < 4; cc++) {
        Bg[cc] = Bt + (size_t)(n0 + wave * 32 + cc * 8 + rl) * K + sc;
        Bl[cc] = Bs + (wave * 4 + cc) * 512;
    }

    f32x16 acc[2] = {};

    for (int k0 = 0; k0 < K; k0 += 64) {
        __syncthreads();
#pragma unroll
        for (int cc = 0; cc < 2; cc++) GLOAD16(Ag[cc] + k0, Al[cc]);
#pragma unroll
        for (int cc = 0; cc < 4; cc++) GLOAD16(Bg[cc] + k0, Bl[cc]);
        __syncthreads();

#pragma unroll
        for (int ks = 0; ks < 4; ks++) {
            const int ch = (((ks * 2 + hi) ^ (l32 & 7))) * 8;
            short8 a  = *(const short8*)(As + (wm + l32) * 64 + ch);
            short8 b0 = *(const short8*)(Bs + (wn + l32) * 64 + ch);
            short8 b1 = *(const short8*)(Bs + (wn + 32 + l32) * 64 + ch);
            acc[0] = MFMA32(a, b0, acc[0]);
            acc[1] = MFMA32(a, b1, acc[1]);
        }
    }

#pragma unroll
    for (int j = 0; j < 2; j++)
#pragma unroll
        for (int r = 0; r < 16; r++) {
            int row = m0 + wm + (r & 3) + 8 * (r >> 2) + 4 * hi;
            int col = n0 + wn + j * 32 + l32;
            C[(size_t)row * 1024 + col] = acc[j][r];
        }
}

// ---------------------------------------------------------------- flash attention (S^T formulation)
// 64-q blocks, LPT grid, GLOAD16 staging into swizzled panels. Q pre-scaled.
__global__ __launch_bounds__(256) void attention_kernel(const unsigned short* Qb,
                                                        const unsigned short* Kb,
                                                        const unsigned short* Vt,
                                                        unsigned short* attn) {
    const int T = 2048;
    const int bi = blockIdx.x;
    const int qb = 31 - (bi >> 6);
    const int hb = bi & 63;
    const int b = hb >> 4, h = hb & 15;
    const int qb0 = qb * 64;
    const int tid = threadIdx.x, wave = tid >> 6, lane = tid & 63;
    const int l16 = lane & 15, quad = lane >> 4;
    const int qw0 = qb0 + wave * 16;

    const unsigned short* Qp  = Qb + (size_t)b * T * 1024 + h * 64;
    const unsigned short* Kp  = Kb + (size_t)b * T * 1024 + h * 64;
    const unsigned short* Vbh = Vt + ((size_t)(b * 16 + h) * 64) * 2048;

    __shared__ unsigned short Ks[2][64 * 32];
    __shared__ unsigned short Vts[2][64 * 32];
    __shared__ unsigned short Ps[4][16 * 40];
    unsigned short* Psw = Ps[wave];

    short8 qf[2];
#pragma unroll
    for (int kd = 0; kd < 2; kd++)
        qf[kd] = *(const short8*)(Qp + (size_t)(qw0 + l16) * 1024 + kd * 32 + quad * 8);

    f32x4 o[4] = {};
    float l_acc = 0.f;

    const int srow = lane >> 2;
    const int scol = (((lane & 3) ^ ((lane >> 3) & 3)) * 8);
    const int sw8  = ((l16 >> 1) & 3) * 8;
    const size_t ktstep = (wave < 2) ? (size_t)64 * 1024 : (size_t)64;
    const size_t cstep  = (wave < 2) ? (size_t)16 * 1024 : (size_t)16 * T;
    const unsigned short* g0 = (wave < 2)
            ? Kp + (size_t)srow * 1024 + wave * 32 + scol
            : Vbh + (size_t)srow * T + (wave - 2) * 32 + scol;
    unsigned short* l0 = (wave < 2) ? Ks[wave] : Vts[wave - 2];

    for (int kt = 0; kt <= qb; kt++) {
        const int tk0 = kt * 64;
        const unsigned short* g = g0 + (size_t)kt * ktstep;
        __syncthreads();
#pragma unroll
        for (int c = 0; c < 4; c++) GLOAD16(g + c * cstep, l0 + c * 512);
        __syncthreads();

#pragma unroll
        for (int th = 0; th < 2; th++) {
            if (tk0 + th * 32 > qw0 + 15) continue;

            f32x4 s[2];
            bool act[2];
#pragma unroll
            for (int mi = 0; mi < 2; mi++) {
                const int t0 = tk0 + (th * 2 + mi) * 16;
                act[mi] = (t0 <= qw0 + 15);
                s[mi] = (f32x4){0.f, 0.f, 0.f, 0.f};
                if (act[mi]) {
                    const int row = (th * 2 + mi) * 16 + l16;
                    short8 kf0 = *(const short8*)(Ks[0] + row * 32 + (quad * 8 ^ sw8));
                    short8 kf1 = *(const short8*)(Ks[1] + row * 32 + (quad * 8 ^ sw8));
                    s[mi] = MFMA16(kf0, qf[0], s[mi]);
                    s[mi] = MFMA16(kf1, qf[1], s[mi]);
                }
            }
#pragma unroll
            for (int mi = 0; mi < 2; mi++) {
                const int t0 = tk0 + (th * 2 + mi) * 16;
                unsigned pk0 = 0, pk1 = 0;
                if (act[mi]) {
                    const bool full = (t0 + 15) <= qw0;
                    float p[4];
#pragma unroll
                    for (int r = 0; r < 4; r++) {
                        float e = __builtin_amdgcn_exp2f(s[mi][r]);
                        if (!full)
                            e = (t0 + quad * 4 + r <= qw0 + l16) ? e : 0.f;
                        p[r] = e;
                    }
                    l_acc += (p[0] + p[1]) + (p[2] + p[3]);
                    pk0 = pack2(p[0], p[1]);
                    pk1 = pack2(p[2], p[3]);
                }
                uint2 pr; pr.x = pk0; pr.y = pk1;
                *(uint2*)(Psw + l16 * 40 + mi * 16 + quad * 4) = pr;
            }
            short8 pf = *(const short8*)(Psw + l16 * 40 + quad * 8);
#pragma unroll
            for (int dt = 0; dt < 4; dt++) {
                short8 vf = *(const short8*)(Vts[th] + (dt * 16 + l16) * 32 + (quad * 8 ^ sw8));
                o[dt] = MFMA16(vf, pf, o[dt]);
            }
        }
    }

    float l = l_acc;
    l += __shfl_xor(l, 16);
    l += __shfl_xor(l, 32);
    const float rl2 = 1.f / l;
    const int q = qw0 + l16;
#pragma unroll
    for (int dt = 0; dt < 4; dt++) {
        ushort4 wv;
        wv.x = f2b(o[dt][0] * rl2);
        wv.y = f2b(o[dt][1] * rl2);
        wv.z = f2b(o[dt][2] * rl2);
        wv.w = f2b(o[dt][3] * rl2);
        *(ushort4*)(attn + (size_t)(b * T + q) * 1024 + h * 64 + dt * 16 + quad * 4) = wv;
    }
}

// ---------------------------------------------------------------- launch
extern "C" void kernel_launch(void* const* d_in, const int* in_sizes, int n_in,
                              void* d_out, int out_size, void* d_ws, size_t ws_size,
                              hipStream_t stream) {
    const float* x     = (const float*)d_in[0]; // (4,2048,1024)
    const float* w_qkv = (const float*)d_in[1]; // (1024,3072)
    const float* w_out = (const float*)d_in[2]; // (1024,1024)
    float* out = (float*)d_out;

    const int M = 8192, D = 1024, E = 3072;
    const size_t MB = 1048576;

    char* ws = (char*)d_ws;
    unsigned short* xb    = (unsigned short*)ws;              // 16 MB
    unsigned short* wqkvT = (unsigned short*)(ws + 16 * MB);  // 6 MB
    unsigned short* woutT = (unsigned short*)(ws + 22 * MB);  // 2 MB
    unsigned short* Qb    = (unsigned short*)(ws + 24 * MB);  // 16 MB (reused as attn out)
    unsigned short* Kb    = (unsigned short*)(ws + 40 * MB);  // 16 MB
    unsigned short* Vt    = (unsigned short*)(ws + 56 * MB);  // 16 MB -> 72 MB total

    cast4_kernel<<<M * D / 4 / 256, 256, 0, stream>>>(x, xb, M * D / 4);
    transpose_cast_f32<<<dim3(E / 64, D / 64), 256, 0, stream>>>(w_qkv, wqkvT, D, E);
    transpose_cast_f32<<<dim3(D / 64, D / 64), 256, 0, stream>>>(w_out, woutT, D, D);

    gemm_qkv<<<dim3(E / 128, M / 128), 256, 0, stream>>>(xb, wqkvT, Qb, Kb, Vt);

    attention_kernel<<<dim3(2048), 256, 0, stream>>>(Qb, Kb, Vt, Qb);

    gemm_out<<<dim3(D / 128, M / 64), 256, 0, stream>>>(Qb, woutT, out);
}